// Round 8
// baseline (317.576 us; speedup 1.0000x reference)
//
#include <hip/hip_runtime.h>
#include <cmath>

#define BB 2
#define SS 2048
#define DD 1024
#define HH 16
#define HDIM 64
#define KDIM 1024
#define EPSF 1e-8f
// 0.125 (1/sqrt(HD)) * log2(e), folded into Q at projection time
#define QSCALE 0.18033688f

typedef __attribute__((ext_vector_type(8))) short bf16x8;
typedef __attribute__((ext_vector_type(4))) float f32x4;
typedef __attribute__((ext_vector_type(16))) float f32x16;

__device__ __forceinline__ ushort f2bf(float x) {
    unsigned u = __builtin_bit_cast(unsigned, x);
    u += 0x7FFFu + ((u >> 16) & 1u);   // RNE
    return (ushort)(u >> 16);
}

// pack two fp32 -> bf16x2 (truncation, 1 v_perm): low = a, high = b
__device__ __forceinline__ unsigned pack_bf16_trunc(float a, float b) {
    return __builtin_amdgcn_perm(__builtin_bit_cast(unsigned, b),
                                 __builtin_bit_cast(unsigned, a), 0x07060302u);
}

// raw v_exp_f32 (2^x): skips OCML range-guard code
__device__ __forceinline__ float exp2_fast(float x) {
    float r;
    asm("v_exp_f32 %0, %1" : "=v"(r) : "v"(x));
    return r;
}

__device__ __forceinline__ void gload_lds16(const ushort* g, ushort* l) {
    __builtin_amdgcn_global_load_lds(
        (const __attribute__((address_space(1))) unsigned*)g,
        (__attribute__((address_space(3))) unsigned*)l, 16, 0, 0);
}

// ---------------------------------------------------------------------------
// Fused fp32->bf16 conversion for hs + 4 weights (dsts contiguous in ws).
// ---------------------------------------------------------------------------
__global__ __launch_bounds__(256) void conv_all(
    const float* __restrict__ hs, const float* __restrict__ wq,
    const float* __restrict__ wk, const float* __restrict__ wv,
    const float* __restrict__ wo, ushort* __restrict__ dst)
{
    const int i = blockIdx.x * 256 + threadIdx.x;   // float4 group index
    const int HS4 = (BB * SS * DD) / 4;             // 1048576
    const int W4 = (DD * DD) / 4;                   // 262144
    const float* src;
    int off;
    if (i < HS4) { src = hs; off = i; }
    else {
        const int j = i - HS4;
        const int seg = j / W4;
        off = j - seg * W4;
        src = (seg == 0) ? wq : (seg == 1) ? wk : (seg == 2) ? wv : wo;
    }
    const float4 v = ((const float4*)src)[off];
    ushort4 o;
    o.x = f2bf(v.x); o.y = f2bf(v.y); o.z = f2bf(v.z); o.w = f2bf(v.w);
    ((ushort4*)dst)[i] = o;
}

// ---------------------------------------------------------------------------
// Kernel 1: fused QKV projection, bf16 MFMA (m97 structure).
// Q pre-scaled by QSCALE so attention softmax is a bare exp2.
// Q,K -> (B,H,S,HD) bf16; V -> (B,H,HD,S) bf16 (transposed).
// ---------------------------------------------------------------------------
__global__ __launch_bounds__(256) void gemm_qkv_mfma(
    const ushort* __restrict__ A,
    const ushort* __restrict__ Wq, const ushort* __restrict__ Wk,
    const ushort* __restrict__ Wv,
    const float* __restrict__ sinp, const float* __restrict__ cosp,
    ushort* __restrict__ Qb, ushort* __restrict__ Kb, ushort* __restrict__ Vtb)
{
    const int cb = blockIdx.y;
    const int z = cb >> 3;
    const int col0 = (cb & 7) * 128;
    const ushort* W = (z == 0) ? Wq : (z == 1) ? Wk : Wv;
    ushort* O = (z == 0) ? Qb : (z == 1) ? Kb : Vtb;
    const int row0 = blockIdx.x * 128;
    const float qs = (z == 0) ? QSCALE : 1.0f;

    __shared__ __align__(16) ushort As[128 * 32];
    __shared__ __align__(16) ushort Bs[128 * 32];

    const int tid = threadIdx.x;
    const int w = tid >> 6, lane = tid & 63;
    const int quad = lane >> 4, l15 = lane & 15;
    const int m_off = (w >> 1) * 64, n_off = (w & 1) * 64;

    f32x4 acc[4][4] = {};

    for (int k0 = 0; k0 < KDIM; k0 += 32) {
#pragma unroll
        for (int it = 0; it < 2; ++it) {
            const int L = (it * 4 + w) * 64 + lane;
            const int r = L >> 2, c8 = (L & 3) * 8;
            gload_lds16(A + (size_t)(row0 + r) * KDIM + k0 + c8, &As[L * 8]);
            gload_lds16(W + (size_t)(col0 + r) * KDIM + k0 + c8, &Bs[L * 8]);
        }
        __syncthreads();
        bf16x8 af[4], bfr[4];
#pragma unroll
        for (int i = 0; i < 4; ++i) {
            af[i]  = *(const bf16x8*)&As[(m_off + i * 16 + l15) * 32 + quad * 8];
            bfr[i] = *(const bf16x8*)&Bs[(n_off + i * 16 + l15) * 32 + quad * 8];
        }
#pragma unroll
        for (int i = 0; i < 4; ++i)
#pragma unroll
            for (int j = 0; j < 4; ++j)
                acc[i][j] = __builtin_amdgcn_mfma_f32_16x16x32_bf16(
                    af[i], bfr[j], acc[i][j], 0, 0, 0);
        __syncthreads();
    }

    const int b = (row0 + m_off) / SS;
#pragma unroll
    for (int mi = 0; mi < 4; ++mi) {
        const int mrow = row0 + m_off + mi * 16 + quad * 4;
#pragma unroll
        for (int ni = 0; ni < 4; ++ni) {
            const int c = col0 + n_off + ni * 16 + l15;
            const int h = c >> 6, e = c & 63;
            const int bh = b * HH + h;
            float outv[4];
#pragma unroll
            for (int r = 0; r < 4; ++r) {
                const int s = (mrow + r) & (SS - 1);
                const float sv = sinp[s * (HDIM / 2) + (e >> 1)];
                const float cv = cosp[s * (HDIM / 2) + (e >> 1)];
                const float v = acc[mi][ni][r];
                const float vp = __shfl_xor(v, 1);
                outv[r] = ((l15 & 1) ? (v * cv + vp * sv) : (v * cv - vp * sv)) * qs;
            }
            if (z < 2) {
#pragma unroll
                for (int r = 0; r < 4; ++r) {
                    const int s = (mrow + r) & (SS - 1);
                    const ushort mine = f2bf(outv[r]);
                    const ushort part = (ushort)__shfl_xor((int)mine, 1);
                    if (!(l15 & 1))
                        *(unsigned*)(O + ((size_t)(bh * SS + s)) * HDIM + e) =
                            (unsigned)mine | ((unsigned)part << 16);
                }
            } else {
                ushort4 pk;
                pk.x = f2bf(outv[0]); pk.y = f2bf(outv[1]);
                pk.z = f2bf(outv[2]); pk.w = f2bf(outv[3]);
                const int s0 = mrow & (SS - 1);
                *(ushort4*)(O + ((size_t)(bh * HDIM + e)) * SS + s0) = pk;
            }
        }
    }
}

// ---------------------------------------------------------------------------
// Kernel 2: flash attention, 32x32x16 bf16 MFMA, S^T formulation, in-block
// key-split. XOR-swizzled LDS (physical chunk = c16 ^ (row&3), 64-B rows):
// frag ds_read_b128s are 2-way (free, m136), staging writes conflict-free.
// Staging via VGPR (uint4 -> ds_write_b128) with next-iteration global loads
// issued right after the barrier (latency hidden under full compute phase).
// Block = 64 q-rows, 4 waves = 2 q-strips x 2 key-phases; shift-free
// softmax; strips merge partials via LDS at the end.
// ---------------------------------------------------------------------------
__global__ __launch_bounds__(256) void attn_mfma(
    const ushort* __restrict__ Qb, const ushort* __restrict__ Kb,
    const ushort* __restrict__ Vtb, ushort* __restrict__ ctx)
{
    const int bh = blockIdx.y;
    const int b = bh / HH, h = bh % HH;
    const int q0 = blockIdx.x * 64;
    const int tid = threadIdx.x;
    const int w = tid >> 6;
    const int lane = tid & 63;
    const int l31 = lane & 31;
    const int g = lane >> 5;
    const int strip = w >> 1;     // q-strip: waves {0,1} -> 0, {2,3} -> 1
    const int phase = w & 1;      // key phase: even/odd 64-key tile

    // [phase][K=0/V=1][hf*64+row][32], XOR-swizzled chunks. 32 KB.
    __shared__ __align__(16) ushort kv[2][2][128][32];

    const ushort* Qh = Qb  + (size_t)bh * SS * HDIM;
    const ushort* Kh = Kb  + (size_t)bh * SS * HDIM;
    const ushort* Vh = Vtb + (size_t)bh * HDIM * SS;

    // Q B-fragments (n = l31 = q-row, k = d)
    const int qrow = q0 + strip * 32 + l31;
    bf16x8 qf[4];
#pragma unroll
    for (int ks = 0; ks < 4; ++ks)
        qf[ks] = *(const bf16x8*)(Qh + (size_t)qrow * HDIM + ks * 16 + g * 8);

    f32x16 cacc[2] = {};
    float lsum = 0.f;

    const int lr = lane >> 2;          // staging row 0..15
    const int c16 = lane & 3;          // 16-B chunk index
    const int lc = c16 * 8;            // ushort col in global
    const int swc = (c16 ^ (lr & 3)) * 8;   // swizzled LDS chunk

    union U32x4 { unsigned u[4]; bf16x8 v; };

    // staging registers: [bq][hf][K/V]
    uint4 sreg[2][2][2];
    auto load_stage = [&](int k0) {
#pragma unroll
        for (int bq = 0; bq < 2; ++bq) {
            const int kb = k0 + bq * 64;
#pragma unroll
            for (int hf = 0; hf < 2; ++hf) {
                sreg[bq][hf][0] = *(const uint4*)(
                    Kh + (size_t)(kb + w * 16 + lr) * HDIM + hf * 32 + lc);
                sreg[bq][hf][1] = *(const uint4*)(
                    Vh + (size_t)(w * 16 + lr) * SS + kb + hf * 32 + lc);
            }
        }
    };
    auto write_stage = [&]() {
#pragma unroll
        for (int bq = 0; bq < 2; ++bq)
#pragma unroll
            for (int hf = 0; hf < 2; ++hf) {
                *(uint4*)&kv[bq][0][hf * 64 + w * 16 + lr][swc] = sreg[bq][hf][0];
                *(uint4*)&kv[bq][1][hf * 64 + w * 16 + lr][swc] = sreg[bq][hf][1];
            }
    };

    load_stage(0);

    for (int k0 = 0; k0 < SS; k0 += 128) {
        __syncthreads();           // consumers of previous tile done
        write_stage();
        __syncthreads();           // tile visible
        if (k0 + 128 < SS) load_stage(k0 + 128);   // prefetch next

        // ---- S^T = K . Q^T on my 64-key tile ----
        f32x16 sacc[2] = {};
#pragma unroll
        for (int kt = 0; kt < 2; ++kt)
#pragma unroll
            for (int ks = 0; ks < 4; ++ks) {
                const int row = kt * 32 + l31;
                const bf16x8 kf = *(const bf16x8*)&kv[phase][0]
                    [(ks >> 1) * 64 + row][(((ks & 1) * 2 + g) ^ (row & 3)) * 8];
                sacc[kt] = __builtin_amdgcn_mfma_f32_32x32x16_bf16(
                    kf, qf[ks], sacc[kt], 0, 0, 0);
            }

        // ---- shift-free softmax + pack P^T pairs ----
        unsigned pk[2][8];
#pragma unroll
        for (int kt = 0; kt < 2; ++kt)
#pragma unroll
            for (int i = 0; i < 8; ++i) {
                const float pa = exp2_fast(sacc[kt][2 * i]);
                const float pb = exp2_fast(sacc[kt][2 * i + 1]);
                lsum += pa + pb;
                pk[kt][i] = pack_bf16_trunc(pa, pb);
            }

        // ---- ctx^T += V^T . P^T ----
#pragma unroll
        for (int ks = 0; ks < 4; ++ks) {
            const int kt = ks >> 1, bq = (ks & 1) * 4;
            const unsigned s0 = (unsigned)__shfl_xor((int)pk[kt][bq + 0], 32);
            const unsigned s1 = (unsigned)__shfl_xor((int)pk[kt][bq + 1], 32);
            const unsigned s2 = (unsigned)__shfl_xor((int)pk[kt][bq + 2], 32);
            const unsigned s3 = (unsigned)__shfl_xor((int)pk[kt][bq + 3], 32);
            U32x4 pf;
            pf.u[0] = g ? s2 : pk[kt][bq + 0];
            pf.u[1] = g ? s3 : pk[kt][bq + 1];
            pf.u[2] = g ? pk[kt][bq + 2] : s0;
            pf.u[3] = g ? pk[kt][bq + 3] : s1;
#pragma unroll
            for (int dt = 0; dt < 2; ++dt) {
                const int row = dt * 32 + l31;
                const bf16x8 vf = *(const bf16x8*)&kv[phase][1]
                    [(ks >> 1) * 64 + row][(((ks & 1) * 2 + g) ^ (row & 3)) * 8];
                cacc[dt] = __builtin_amdgcn_mfma_f32_32x32x16_bf16(
                    vf, pf.v, cacc[dt], 0, 0, 0);
            }
        }
    }

    // within-wave: partner half holds the other 32 keys of each tile
    lsum += __shfl_xor(lsum, 32);

    // ---- strip merge: phase-1 wave hands partials to phase-0 wave ----
    __syncthreads();
    float* mlds = (float*)kv;
    const int mbase = strip * 2112 + lane * 33;   // stride 33: conflict-free
    if (phase == 1) {
#pragma unroll
        for (int dt = 0; dt < 2; ++dt)
#pragma unroll
            for (int i = 0; i < 16; ++i) mlds[mbase + dt * 16 + i] = cacc[dt][i];
        mlds[mbase + 32] = lsum;
    }
    __syncthreads();
    if (phase == 0) {
#pragma unroll
        for (int dt = 0; dt < 2; ++dt)
#pragma unroll
            for (int i = 0; i < 16; ++i) cacc[dt][i] += mlds[mbase + dt * 16 + i];
        lsum += mlds[mbase + 32];
        const float inv = 1.f / lsum;

        // epilogue: C-layout col = l31 = q, row = (r&3)+8*(r>>2)+4g = d-local
        const size_t obase = ((size_t)(b * SS + qrow)) * DD + h * HDIM;
#pragma unroll
        for (int dt = 0; dt < 2; ++dt)
#pragma unroll
            for (int t = 0; t < 4; ++t) {
                ushort4 o;
                o.x = f2bf(cacc[dt][t * 4 + 0] * inv);
                o.y = f2bf(cacc[dt][t * 4 + 1] * inv);
                o.z = f2bf(cacc[dt][t * 4 + 2] * inv);
                o.w = f2bf(cacc[dt][t * 4 + 3] * inv);
                *(ushort4*)(ctx + obase + dt * 32 + t * 8 + g * 4) = o;
            }
    }
}

// ---------------------------------------------------------------------------
// Kernel 3: output projection, bf16 MFMA, 128x64 tile (512 blocks = 2/CU),
// + bias, fp32 out (B*S, D).
// ---------------------------------------------------------------------------
__global__ __launch_bounds__(256) void gemm_out_mfma(
    const ushort* __restrict__ A, const ushort* __restrict__ W,
    const float* __restrict__ bias, float* __restrict__ Out)
{
    const int row0 = blockIdx.x * 128;
    const int col0 = blockIdx.y * 64;

    __shared__ __align__(16) ushort As[128 * 32];
    __shared__ __align__(16) ushort Bs[64 * 32];

    const int tid = threadIdx.x;
    const int w = tid >> 6, lane = tid & 63;
    const int quad = lane >> 4, l15 = lane & 15;
    const int m_off = (w >> 1) * 64, n_off = (w & 1) * 32;

    f32x4 acc[4][2] = {};

    for (int k0 = 0; k0 < KDIM; k0 += 32) {
#pragma unroll
        for (int it = 0; it < 2; ++it) {
            const int L = (it * 4 + w) * 64 + lane;
            const int r = L >> 2, c8 = (L & 3) * 8;
            gload_lds16(A + (size_t)(row0 + r) * KDIM + k0 + c8, &As[L * 8]);
        }
        {
            const int L = w * 64 + lane;
            const int r = L >> 2, c8 = (L & 3) * 8;
            gload_lds16(W + (size_t)(col0 + r) * KDIM + k0 + c8, &Bs[L * 8]);
        }
        __syncthreads();
        bf16x8 af[4], bfr[2];
#pragma unroll
        for (int i = 0; i < 4; ++i)
            af[i] = *(const bf16x8*)&As[(m_off + i * 16 + l15) * 32 + quad * 8];
#pragma unroll
        for (int j = 0; j < 2; ++j)
            bfr[j] = *(const bf16x8*)&Bs[(n_off + j * 16 + l15) * 32 + quad * 8];
#pragma unroll
        for (int i = 0; i < 4; ++i)
#pragma unroll
            for (int j = 0; j < 2; ++j)
                acc[i][j] = __builtin_amdgcn_mfma_f32_16x16x32_bf16(
                    af[i], bfr[j], acc[i][j], 0, 0, 0);
        __syncthreads();
    }

#pragma unroll
    for (int mi = 0; mi < 4; ++mi) {
        const int mrow = row0 + m_off + mi * 16 + quad * 4;
#pragma unroll
        for (int ni = 0; ni < 2; ++ni) {
            const int c = col0 + n_off + ni * 16 + l15;
            const float bv = bias[c];
#pragma unroll
            for (int r = 0; r < 4; ++r)
                Out[(size_t)(mrow + r) * DD + c] = acc[mi][ni][r] + bv;
        }
    }
}

// ---------------------------------------------------------------------------
// Kernel 4: residual add + RMSNorm. One block per token.
// ---------------------------------------------------------------------------
__global__ __launch_bounds__(256) void resid_rmsnorm(
    const float* __restrict__ proj, const float* __restrict__ hs,
    const float* __restrict__ scale, float* __restrict__ out)
{
    const int t = blockIdx.x;
    const int tid = threadIdx.x;
    const size_t base = (size_t)t * DD + tid * 4;

    const float4 p4 = *(const float4*)(proj + base);
    const float4 h4 = *(const float4*)(hs + base);
    float x0 = p4.x + h4.x, x1 = p4.y + h4.y, x2 = p4.z + h4.z, x3 = p4.w + h4.w;
    float ss = x0 * x0 + x1 * x1 + x2 * x2 + x3 * x3;

#pragma unroll
    for (int off = 1; off < 64; off <<= 1) ss += __shfl_xor(ss, off);

    __shared__ float wsum[4];
    if ((tid & 63) == 0) wsum[tid >> 6] = ss;
    __syncthreads();
    const float total = wsum[0] + wsum[1] + wsum[2] + wsum[3];
    const float inv = 1.f / (sqrtf(total * (1.f / DD)) + EPSF);

    const float4 s4 = *(const float4*)(scale + tid * 4);
    float4 o;
    o.x = s4.x * x0 * inv;
    o.y = s4.y * x1 * inv;
    o.z = s4.z * x2 * inv;
    o.w = s4.w * x3 * inv;
    *(float4*)(out + base) = o;
}

// ---------------------------------------------------------------------------
extern "C" void kernel_launch(void* const* d_in, const int* in_sizes, int n_in,
                              void* d_out, int out_size, void* d_ws, size_t ws_size,
                              hipStream_t stream) {
    const float* hs    = (const float*)d_in[0];
    const float* sinp  = (const float*)d_in[1];
    const float* cosp  = (const float*)d_in[2];
    const float* wq    = (const float*)d_in[3];
    const float* wk    = (const float*)d_in[4];
    const float* wv    = (const float*)d_in[5];
    const float* wo    = (const float*)d_in[6];
    const float* bo    = (const float*)d_in[7];
    const float* scale = (const float*)d_in[8];
    float* out = (float*)d_out;

    unsigned char* wsb = (unsigned char*)d_ws;
    const size_t MAT = (size_t)BB * SS * DD;
    const size_t WN  = (size_t)DD * DD;
    ushort* Abf = (ushort*)wsb;           // contiguous: Abf, Wqb, Wkb, Wvb, Wob
    ushort* Wqb = Abf + MAT;
    ushort* Wkb = Wqb + WN;
    ushort* Wvb = Wkb + WN;
    ushort* Wob = Wvb + WN;
    ushort* Qb  = Wob + WN;
    ushort* Kb  = Qb + MAT;
    ushort* Vtb = Kb + MAT;
    ushort* ctxb = Vtb + MAT;
    float* proj = (float*)(ctxb + MAT);

    const int nconv4 = (int)((MAT + 4 * WN) / 4);    // 2M float4 groups
    conv_all<<<dim3(nconv4 / 256), 256, 0, stream>>>(hs, wq, wk, wv, wo, Abf);

    gemm_qkv_mfma<<<dim3(32, 24), 256, 0, stream>>>(Abf, Wqb, Wkb, Wvb,
                                                    sinp, cosp, Qb, Kb, Vtb);
    attn_mfma<<<dim3(SS / 64, BB * HH), 256, 0, stream>>>(Qb, Kb, Vtb, ctxb);
    gemm_out_mfma<<<dim3(32, 16), 256, 0, stream>>>(ctxb, Wob, bo, proj);
    resid_rmsnorm<<<dim3(BB * SS), 256, 0, stream>>>(proj, hs, scale, out);
}

// Round 9
// 219.627 us; speedup vs baseline: 1.4460x; 1.4460x over previous
//
#include <hip/hip_runtime.h>
#include <cmath>

#define BB 2
#define SS 2048
#define DD 1024
#define HH 16
#define HDIM 64
#define KDIM 1024
#define EPSF 1e-8f
// 0.125 (1/sqrt(HD)) * log2(e), folded into Q at projection time
#define QSCALE 0.18033688f

typedef __attribute__((ext_vector_type(8))) short bf16x8;
typedef __attribute__((ext_vector_type(4))) float f32x4;
typedef __attribute__((ext_vector_type(16))) float f32x16;

__device__ __forceinline__ ushort f2bf(float x) {
    unsigned u = __builtin_bit_cast(unsigned, x);
    u += 0x7FFFu + ((u >> 16) & 1u);   // RNE
    return (ushort)(u >> 16);
}

// pack two fp32 -> bf16x2 (truncation, 1 v_perm): low = a, high = b
__device__ __forceinline__ unsigned pack_bf16_trunc(float a, float b) {
    return __builtin_amdgcn_perm(__builtin_bit_cast(unsigned, b),
                                 __builtin_bit_cast(unsigned, a), 0x07060302u);
}

// raw v_exp_f32 (2^x): skips OCML range-guard code
__device__ __forceinline__ float exp2_fast(float x) {
    float r;
    asm("v_exp_f32 %0, %1" : "=v"(r) : "v"(x));
    return r;
}

__device__ __forceinline__ void gload_lds16(const ushort* g, ushort* l) {
    __builtin_amdgcn_global_load_lds(
        (const __attribute__((address_space(1))) unsigned*)g,
        (__attribute__((address_space(3))) unsigned*)l, 16, 0, 0);
}

// ---------------------------------------------------------------------------
// Fused fp32->bf16 conversion for hs + 4 weights (dsts contiguous in ws).
// ---------------------------------------------------------------------------
__global__ __launch_bounds__(256) void conv_all(
    const float* __restrict__ hs, const float* __restrict__ wq,
    const float* __restrict__ wk, const float* __restrict__ wv,
    const float* __restrict__ wo, ushort* __restrict__ dst)
{
    const int i = blockIdx.x * 256 + threadIdx.x;   // float4 group index
    const int HS4 = (BB * SS * DD) / 4;             // 1048576
    const int W4 = (DD * DD) / 4;                   // 262144
    const float* src;
    int off;
    if (i < HS4) { src = hs; off = i; }
    else {
        const int j = i - HS4;
        const int seg = j / W4;
        off = j - seg * W4;
        src = (seg == 0) ? wq : (seg == 1) ? wk : (seg == 2) ? wv : wo;
    }
    const float4 v = ((const float4*)src)[off];
    ushort4 o;
    o.x = f2bf(v.x); o.y = f2bf(v.y); o.z = f2bf(v.z); o.w = f2bf(v.w);
    ((ushort4*)dst)[i] = o;
}

// ---------------------------------------------------------------------------
// Kernel 1: fused QKV projection, bf16 MFMA (m97 structure).
// Q pre-scaled by QSCALE so attention softmax is a bare exp2.
// Q,K -> (B,H,S,HD) bf16; V -> (B,H,HD,S) bf16 (transposed).
// ---------------------------------------------------------------------------
__global__ __launch_bounds__(256) void gemm_qkv_mfma(
    const ushort* __restrict__ A,
    const ushort* __restrict__ Wq, const ushort* __restrict__ Wk,
    const ushort* __restrict__ Wv,
    const float* __restrict__ sinp, const float* __restrict__ cosp,
    ushort* __restrict__ Qb, ushort* __restrict__ Kb, ushort* __restrict__ Vtb)
{
    const int cb = blockIdx.y;
    const int z = cb >> 3;
    const int col0 = (cb & 7) * 128;
    const ushort* W = (z == 0) ? Wq : (z == 1) ? Wk : Wv;
    ushort* O = (z == 0) ? Qb : (z == 1) ? Kb : Vtb;
    const int row0 = blockIdx.x * 128;
    const float qs = (z == 0) ? QSCALE : 1.0f;

    __shared__ __align__(16) ushort As[128 * 32];
    __shared__ __align__(16) ushort Bs[128 * 32];

    const int tid = threadIdx.x;
    const int w = tid >> 6, lane = tid & 63;
    const int quad = lane >> 4, l15 = lane & 15;
    const int m_off = (w >> 1) * 64, n_off = (w & 1) * 64;

    f32x4 acc[4][4] = {};

    for (int k0 = 0; k0 < KDIM; k0 += 32) {
#pragma unroll
        for (int it = 0; it < 2; ++it) {
            const int L = (it * 4 + w) * 64 + lane;
            const int r = L >> 2, c8 = (L & 3) * 8;
            gload_lds16(A + (size_t)(row0 + r) * KDIM + k0 + c8, &As[L * 8]);
            gload_lds16(W + (size_t)(col0 + r) * KDIM + k0 + c8, &Bs[L * 8]);
        }
        __syncthreads();
        bf16x8 af[4], bfr[4];
#pragma unroll
        for (int i = 0; i < 4; ++i) {
            af[i]  = *(const bf16x8*)&As[(m_off + i * 16 + l15) * 32 + quad * 8];
            bfr[i] = *(const bf16x8*)&Bs[(n_off + i * 16 + l15) * 32 + quad * 8];
        }
#pragma unroll
        for (int i = 0; i < 4; ++i)
#pragma unroll
            for (int j = 0; j < 4; ++j)
                acc[i][j] = __builtin_amdgcn_mfma_f32_16x16x32_bf16(
                    af[i], bfr[j], acc[i][j], 0, 0, 0);
        __syncthreads();
    }

    const int b = (row0 + m_off) / SS;
#pragma unroll
    for (int mi = 0; mi < 4; ++mi) {
        const int mrow = row0 + m_off + mi * 16 + quad * 4;
#pragma unroll
        for (int ni = 0; ni < 4; ++ni) {
            const int c = col0 + n_off + ni * 16 + l15;
            const int h = c >> 6, e = c & 63;
            const int bh = b * HH + h;
            float outv[4];
#pragma unroll
            for (int r = 0; r < 4; ++r) {
                const int s = (mrow + r) & (SS - 1);
                const float sv = sinp[s * (HDIM / 2) + (e >> 1)];
                const float cv = cosp[s * (HDIM / 2) + (e >> 1)];
                const float v = acc[mi][ni][r];
                const float vp = __shfl_xor(v, 1);
                outv[r] = ((l15 & 1) ? (v * cv + vp * sv) : (v * cv - vp * sv)) * qs;
            }
            if (z < 2) {
#pragma unroll
                for (int r = 0; r < 4; ++r) {
                    const int s = (mrow + r) & (SS - 1);
                    const ushort mine = f2bf(outv[r]);
                    const ushort part = (ushort)__shfl_xor((int)mine, 1);
                    if (!(l15 & 1))
                        *(unsigned*)(O + ((size_t)(bh * SS + s)) * HDIM + e) =
                            (unsigned)mine | ((unsigned)part << 16);
                }
            } else {
                ushort4 pk;
                pk.x = f2bf(outv[0]); pk.y = f2bf(outv[1]);
                pk.z = f2bf(outv[2]); pk.w = f2bf(outv[3]);
                const int s0 = mrow & (SS - 1);
                *(ushort4*)(O + ((size_t)(bh * HDIM + e)) * SS + s0) = pk;
            }
        }
    }
}

// ---------------------------------------------------------------------------
// Kernel 2: flash attention, 32x32x16 bf16 MFMA, S^T formulation, in-block
// key-split, XOR-swizzled LDS, VGPR staging with register prefetch.
// Staging registers are EIGHT NAMED uint4 SCALARS (no array, no lambda):
// lambdas capturing an array by reference defeated SROA in R8 and spilled
// 434 MB to scratch -- macros + scalars keep them in VGPRs.
// ---------------------------------------------------------------------------
__global__ __launch_bounds__(256) void attn_mfma(
    const ushort* __restrict__ Qb, const ushort* __restrict__ Kb,
    const ushort* __restrict__ Vtb, ushort* __restrict__ ctx)
{
    const int bh = blockIdx.y;
    const int b = bh / HH, h = bh % HH;
    const int q0 = blockIdx.x * 64;
    const int tid = threadIdx.x;
    const int w = tid >> 6;
    const int lane = tid & 63;
    const int l31 = lane & 31;
    const int g = lane >> 5;
    const int strip = w >> 1;     // q-strip: waves {0,1} -> 0, {2,3} -> 1
    const int phase = w & 1;      // key phase: even/odd 64-key tile

    // [phase][K=0/V=1][hf*64+row][32], XOR-swizzled chunks. 32 KB.
    __shared__ __align__(16) ushort kv[2][2][128][32];

    const ushort* Qh = Qb  + (size_t)bh * SS * HDIM;
    const ushort* Kh = Kb  + (size_t)bh * SS * HDIM;
    const ushort* Vh = Vtb + (size_t)bh * HDIM * SS;

    // Q B-fragments (n = l31 = q-row, k = d)
    const int qrow = q0 + strip * 32 + l31;
    bf16x8 qf[4];
#pragma unroll
    for (int ks = 0; ks < 4; ++ks)
        qf[ks] = *(const bf16x8*)(Qh + (size_t)qrow * HDIM + ks * 16 + g * 8);

    f32x16 cacc[2] = {};
    float lsum = 0.f;

    const int lr = lane >> 2;          // staging row 0..15
    const int c16 = lane & 3;          // 16-B chunk index
    const int lc = c16 * 8;            // ushort col in global
    const int swc = (c16 ^ (lr & 3)) * 8;   // swizzled LDS chunk

    union U32x4 { unsigned u[4]; bf16x8 v; };

    // named staging registers (bq 0/1 x hf 0/1 for K and V)
    uint4 rk00, rk01, rk10, rk11, rv00, rv01, rv10, rv11;

#define LOAD_STAGE(K0)                                                        \
    do {                                                                      \
        const ushort* Kb_ = Kh + (size_t)((K0) + w * 16 + lr) * HDIM + lc;    \
        const ushort* Vb_ = Vh + (size_t)(w * 16 + lr) * SS + (K0) + lc;      \
        rk00 = *(const uint4*)(Kb_);                                          \
        rk01 = *(const uint4*)(Kb_ + 32);                                     \
        rk10 = *(const uint4*)(Kb_ + (size_t)64 * HDIM);                      \
        rk11 = *(const uint4*)(Kb_ + (size_t)64 * HDIM + 32);                 \
        rv00 = *(const uint4*)(Vb_);                                          \
        rv01 = *(const uint4*)(Vb_ + 32);                                     \
        rv10 = *(const uint4*)(Vb_ + 64);                                     \
        rv11 = *(const uint4*)(Vb_ + 96);                                     \
    } while (0)

#define WRITE_STAGE()                                                         \
    do {                                                                      \
        *(uint4*)&kv[0][0][     w * 16 + lr][swc] = rk00;                     \
        *(uint4*)&kv[0][0][64 + w * 16 + lr][swc] = rk01;                     \
        *(uint4*)&kv[1][0][     w * 16 + lr][swc] = rk10;                     \
        *(uint4*)&kv[1][0][64 + w * 16 + lr][swc] = rk11;                     \
        *(uint4*)&kv[0][1][     w * 16 + lr][swc] = rv00;                     \
        *(uint4*)&kv[0][1][64 + w * 16 + lr][swc] = rv01;                     \
        *(uint4*)&kv[1][1][     w * 16 + lr][swc] = rv10;                     \
        *(uint4*)&kv[1][1][64 + w * 16 + lr][swc] = rv11;                     \
    } while (0)

    // Note V layout: row = d-dim (w*16+lr), col = key; bq=1 keys are +64 in
    // the s direction and land in kv[1][1]; hf here splits the KEY dim for V
    // (rv01 is keys 32..63 of bq=0 -> kv[0][1][64+...]).

    LOAD_STAGE(0);

    for (int k0 = 0; k0 < SS; k0 += 128) {
        __syncthreads();           // consumers of previous tile done
        WRITE_STAGE();
        __syncthreads();           // tile visible
        if (k0 + 128 < SS) LOAD_STAGE(k0 + 128);   // prefetch next

        // ---- S^T = K . Q^T on my 64-key tile ----
        f32x16 sacc[2] = {};
#pragma unroll
        for (int kt = 0; kt < 2; ++kt)
#pragma unroll
            for (int ks = 0; ks < 4; ++ks) {
                const int row = kt * 32 + l31;
                const bf16x8 kf = *(const bf16x8*)&kv[phase][0]
                    [(ks >> 1) * 64 + row][(((ks & 1) * 2 + g) ^ (row & 3)) * 8];
                sacc[kt] = __builtin_amdgcn_mfma_f32_32x32x16_bf16(
                    kf, qf[ks], sacc[kt], 0, 0, 0);
            }

        // ---- shift-free softmax + pack P^T pairs ----
        unsigned pk[2][8];
#pragma unroll
        for (int kt = 0; kt < 2; ++kt)
#pragma unroll
            for (int i = 0; i < 8; ++i) {
                const float pa = exp2_fast(sacc[kt][2 * i]);
                const float pb = exp2_fast(sacc[kt][2 * i + 1]);
                lsum += pa + pb;
                pk[kt][i] = pack_bf16_trunc(pa, pb);
            }

        // ---- ctx^T += V^T . P^T ----
#pragma unroll
        for (int ks = 0; ks < 4; ++ks) {
            const int kt = ks >> 1, bq = (ks & 1) * 4;
            const unsigned s0 = (unsigned)__shfl_xor((int)pk[kt][bq + 0], 32);
            const unsigned s1 = (unsigned)__shfl_xor((int)pk[kt][bq + 1], 32);
            const unsigned s2 = (unsigned)__shfl_xor((int)pk[kt][bq + 2], 32);
            const unsigned s3 = (unsigned)__shfl_xor((int)pk[kt][bq + 3], 32);
            U32x4 pf;
            pf.u[0] = g ? s2 : pk[kt][bq + 0];
            pf.u[1] = g ? s3 : pk[kt][bq + 1];
            pf.u[2] = g ? pk[kt][bq + 2] : s0;
            pf.u[3] = g ? pk[kt][bq + 3] : s1;
#pragma unroll
            for (int dt = 0; dt < 2; ++dt) {
                const int row = dt * 32 + l31;
                const bf16x8 vf = *(const bf16x8*)&kv[phase][1]
                    [(ks >> 1) * 64 + row][(((ks & 1) * 2 + g) ^ (row & 3)) * 8];
                cacc[dt] = __builtin_amdgcn_mfma_f32_32x32x16_bf16(
                    vf, pf.v, cacc[dt], 0, 0, 0);
            }
        }
    }

    // within-wave: partner half holds the other 32 keys of each tile
    lsum += __shfl_xor(lsum, 32);

    // ---- strip merge: phase-1 wave hands partials to phase-0 wave ----
    __syncthreads();
    float* mlds = (float*)kv;
    const int mbase = strip * 2112 + lane * 33;   // stride 33: conflict-free
    if (phase == 1) {
#pragma unroll
        for (int dt = 0; dt < 2; ++dt)
#pragma unroll
            for (int i = 0; i < 16; ++i) mlds[mbase + dt * 16 + i] = cacc[dt][i];
        mlds[mbase + 32] = lsum;
    }
    __syncthreads();
    if (phase == 0) {
#pragma unroll
        for (int dt = 0; dt < 2; ++dt)
#pragma unroll
            for (int i = 0; i < 16; ++i) cacc[dt][i] += mlds[mbase + dt * 16 + i];
        lsum += mlds[mbase + 32];
        const float inv = 1.f / lsum;

        // epilogue: C-layout col = l31 = q, row = (r&3)+8*(r>>2)+4g = d-local
        const size_t obase = ((size_t)(b * SS + qrow)) * DD + h * HDIM;
#pragma unroll
        for (int dt = 0; dt < 2; ++dt)
#pragma unroll
            for (int t = 0; t < 4; ++t) {
                ushort4 o;
                o.x = f2bf(cacc[dt][t * 4 + 0] * inv);
                o.y = f2bf(cacc[dt][t * 4 + 1] * inv);
                o.z = f2bf(cacc[dt][t * 4 + 2] * inv);
                o.w = f2bf(cacc[dt][t * 4 + 3] * inv);
                *(ushort4*)(ctx + obase + dt * 32 + t * 8 + g * 4) = o;
            }
    }
#undef LOAD_STAGE
#undef WRITE_STAGE
}

// ---------------------------------------------------------------------------
// Kernel 3: output projection, bf16 MFMA, 128x64 tile (512 blocks = 2/CU),
// + bias, fp32 out (B*S, D).
// ---------------------------------------------------------------------------
__global__ __launch_bounds__(256) void gemm_out_mfma(
    const ushort* __restrict__ A, const ushort* __restrict__ W,
    const float* __restrict__ bias, float* __restrict__ Out)
{
    const int row0 = blockIdx.x * 128;
    const int col0 = blockIdx.y * 64;

    __shared__ __align__(16) ushort As[128 * 32];
    __shared__ __align__(16) ushort Bs[64 * 32];

    const int tid = threadIdx.x;
    const int w = tid >> 6, lane = tid & 63;
    const int quad = lane >> 4, l15 = lane & 15;
    const int m_off = (w >> 1) * 64, n_off = (w & 1) * 32;

    f32x4 acc[4][2] = {};

    for (int k0 = 0; k0 < KDIM; k0 += 32) {
#pragma unroll
        for (int it = 0; it < 2; ++it) {
            const int L = (it * 4 + w) * 64 + lane;
            const int r = L >> 2, c8 = (L & 3) * 8;
            gload_lds16(A + (size_t)(row0 + r) * KDIM + k0 + c8, &As[L * 8]);
        }
        {
            const int L = w * 64 + lane;
            const int r = L >> 2, c8 = (L & 3) * 8;
            gload_lds16(W + (size_t)(col0 + r) * KDIM + k0 + c8, &Bs[L * 8]);
        }
        __syncthreads();
        bf16x8 af[4], bfr[2];
#pragma unroll
        for (int i = 0; i < 4; ++i)
            af[i] = *(const bf16x8*)&As[(m_off + i * 16 + l15) * 32 + quad * 8];
#pragma unroll
        for (int j = 0; j < 2; ++j)
            bfr[j] = *(const bf16x8*)&Bs[(n_off + j * 16 + l15) * 32 + quad * 8];
#pragma unroll
        for (int i = 0; i < 4; ++i)
#pragma unroll
            for (int j = 0; j < 2; ++j)
                acc[i][j] = __builtin_amdgcn_mfma_f32_16x16x32_bf16(
                    af[i], bfr[j], acc[i][j], 0, 0, 0);
        __syncthreads();
    }

#pragma unroll
    for (int mi = 0; mi < 4; ++mi) {
        const int mrow = row0 + m_off + mi * 16 + quad * 4;
#pragma unroll
        for (int ni = 0; ni < 2; ++ni) {
            const int c = col0 + n_off + ni * 16 + l15;
            const float bv = bias[c];
#pragma unroll
            for (int r = 0; r < 4; ++r)
                Out[(size_t)(mrow + r) * DD + c] = acc[mi][ni][r] + bv;
        }
    }
}

// ---------------------------------------------------------------------------
// Kernel 4: residual add + RMSNorm. One block per token.
// ---------------------------------------------------------------------------
__global__ __launch_bounds__(256) void resid_rmsnorm(
    const float* __restrict__ proj, const float* __restrict__ hs,
    const float* __restrict__ scale, float* __restrict__ out)
{
    const int t = blockIdx.x;
    const int tid = threadIdx.x;
    const size_t base = (size_t)t * DD + tid * 4;

    const float4 p4 = *(const float4*)(proj + base);
    const float4 h4 = *(const float4*)(hs + base);
    float x0 = p4.x + h4.x, x1 = p4.y + h4.y, x2 = p4.z + h4.z, x3 = p4.w + h4.w;
    float ss = x0 * x0 + x1 * x1 + x2 * x2 + x3 * x3;

#pragma unroll
    for (int off = 1; off < 64; off <<= 1) ss += __shfl_xor(ss, off);

    __shared__ float wsum[4];
    if ((tid & 63) == 0) wsum[tid >> 6] = ss;
    __syncthreads();
    const float total = wsum[0] + wsum[1] + wsum[2] + wsum[3];
    const float inv = 1.f / (sqrtf(total * (1.f / DD)) + EPSF);

    const float4 s4 = *(const float4*)(scale + tid * 4);
    float4 o;
    o.x = s4.x * x0 * inv;
    o.y = s4.y * x1 * inv;
    o.z = s4.z * x2 * inv;
    o.w = s4.w * x3 * inv;
    *(float4*)(out + base) = o;
}

// ---------------------------------------------------------------------------
extern "C" void kernel_launch(void* const* d_in, const int* in_sizes, int n_in,
                              void* d_out, int out_size, void* d_ws, size_t ws_size,
                              hipStream_t stream) {
    const float* hs    = (const float*)d_in[0];
    const float* sinp  = (const float*)d_in[1];
    const float* cosp  = (const float*)d_in[2];
    const float* wq    = (const float*)d_in[3];
    const float* wk    = (const float*)d_in[4];
    const float* wv    = (const float*)d_in[5];
    const float* wo    = (const float*)d_in[6];
    const float* bo    = (const float*)d_in[7];
    const float* scale = (const float*)d_in[8];
    float* out = (float*)d_out;

    unsigned char* wsb = (unsigned char*)d_ws;
    const size_t MAT = (size_t)BB * SS * DD;
    const size_t WN  = (size_t)DD * DD;
    ushort* Abf = (ushort*)wsb;           // contiguous: Abf, Wqb, Wkb, Wvb, Wob
    ushort* Wqb = Abf + MAT;
    ushort* Wkb = Wqb + WN;
    ushort* Wvb = Wkb + WN;
    ushort* Wob = Wvb + WN;
    ushort* Qb  = Wob + WN;
    ushort* Kb  = Qb + MAT;
    ushort* Vtb = Kb + MAT;
    ushort* ctxb = Vtb + MAT;
    float* proj = (float*)(ctxb + MAT);

    const int nconv4 = (int)((MAT + 4 * WN) / 4);    // 2M float4 groups
    conv_all<<<dim3(nconv4 / 256), 256, 0, stream>>>(hs, wq, wk, wv, wo, Abf);

    gemm_qkv_mfma<<<dim3(32, 24), 256, 0, stream>>>(Abf, Wqb, Wkb, Wvb,
                                                    sinp, cosp, Qb, Kb, Vtb);
    attn_mfma<<<dim3(SS / 64, BB * HH), 256, 0, stream>>>(Qb, Kb, Vtb, ctxb);
    gemm_out_mfma<<<dim3(32, 16), 256, 0, stream>>>(ctxb, Wob, bo, proj);
    resid_rmsnorm<<<dim3(BB * SS), 256, 0, stream>>>(proj, hs, scale, out);
}